// Round 4
// baseline (804.211 us; speedup 1.0000x reference)
//
#include <hip/hip_runtime.h>
#include <hip/hip_fp16.h>

// Problem constants (fixed by the harness' setup_inputs):
//   B=1000, L=50, D=128, NUM_ITEM=100000, NBIN=10, T=25500, n_edges=51000
#define D    128
#define L    50
#define G3   384          // 3*D
#define NBIN 10
#define XT   32           // tokens per xps block

// final-matmul tile params (128x128, A in regs, B in 32KB LDS)
#define FBM 128
#define FBN 128

typedef float f32x4 __attribute__((ext_vector_type(4)));
typedef short s16x8 __attribute__((ext_vector_type(8)));

#define MFMA_B16(a,b,c) __builtin_amdgcn_mfma_f32_16x16x32_bf16(a,b,c,0,0,0)

__device__ __forceinline__ float sigm(float x){ return 1.f/(1.f+__expf(-x)); }
__device__ __forceinline__ float tanh_fast(float x){
  float xx = fminf(fmaxf(x,-15.f),15.f);
  float e  = __expf(2.f*xx);
  return (e-1.f)/(e+1.f);
}

// split fp32 -> (hi bf16, lo bf16): x ~= hi + lo to ~2^-17 rel
#define SPLIT1(x, hu, lu) { unsigned u_ = __float_as_uint(x); hu = u_ >> 16; \
  float hf_ = __uint_as_float(u_ & 0xffff0000u); float lf_ = (x) - hf_; \
  lu = __float_as_uint(lf_) >> 16; }

__device__ __forceinline__ void split8(f32x4 a, f32x4 b, s16x8& hi, s16x8& lo){
  s16x8 h, l;
#pragma unroll
  for (int i=0;i<4;++i){
    unsigned hu, lu;
    SPLIT1(a[i], hu, lu)
    h[i] = (short)hu; l[i] = (short)lu;
  }
#pragma unroll
  for (int i=0;i<4;++i){
    unsigned hu, lu;
    SPLIT1(b[i], hu, lu)
    h[4+i] = (short)hu; l[4+i] = (short)lu;
  }
  hi = h; lo = l;
}

// ---------------- mega prep: tables + h0 init + zeros + tokmap ----------------
__global__ void k_prep(const float* __restrict__ bin_emb,
                       const float* __restrict__ Wf, const float* __restrict__ bf,
                       const float* __restrict__ Wb, const float* __restrict__ bb,
                       const float* __restrict__ item_emb, const int* __restrict__ items,
                       float* __restrict__ tabf, float* __restrict__ tabb,
                       float* __restrict__ accA, float* __restrict__ xB, float* __restrict__ xC,
                       float* __restrict__ cpad, int* __restrict__ tokmap,
                       long long NG, long long BLD, int BL){
  const long long r1 = 7680, r2 = r1 + NG, r3 = r2 + NG, r4 = r3 + BLD;
  const long long total = r4 + BL;
  for (long long i = (long long)blockIdx.x*256 + threadIdx.x; i < total;
       i += (long long)gridDim.x*256){
    if (i < r1){
      int id = (int)i; int dirr = id / (NBIN*G3); int rr = id % (NBIN*G3);
      int v = rr / G3, g = rr % G3;
      const float* W  = dirr ? Wb : Wf;
      const float* bi = dirr ? bb : bf;
      float a = bi[g];
      for (int d = 0; d < D; ++d) a += bin_emb[v*D+d]*W[g*D+d];
      (dirr ? tabb : tabf)[v*G3+g] = a;
    } else if (i < r2){
      long long k = i - r1;
      int nn = (int)(k>>7), d = (int)(k&127);
      float v = item_emb[(size_t)items[nn]*D + d];
      accA[k] = v; xB[k] = v;
    } else if (i < r3){
      xC[i - r2] = 0.f;
    } else if (i < r4){
      cpad[i - r3] = 0.f;
    } else {
      tokmap[i - r4] = -1;
    }
  }
}

// ---------------- GCN scatter + fused accum/zero ----------------
__global__ void k_scatter(const float* __restrict__ x, float* __restrict__ xn,
                          const int* __restrict__ src, const int* __restrict__ dst,
                          const float* __restrict__ ew, int ne){
  int i = blockIdx.x*256 + threadIdx.x;
  if (i >= ne*D) return;
  int e = i >> 7, d = i & (D-1);
  atomicAdd(&xn[(size_t)dst[e]*D + d], x[(size_t)src[e]*D + d]*ew[e]);
}
__global__ void k_accum_zero(float* __restrict__ acc, const float* __restrict__ xn,
                             float* __restrict__ xz, int n, int dz){
  int i = blockIdx.x*256 + threadIdx.x;
  if (i < n){ acc[i] += xn[i]; if (dz) xz[i] = 0.f; }
}

// ============ MFMA GRU, fragment-local elementwise ============
// W rows permuted per wave: wave w owns gates {j, D+j, 2D+j} for j in [16w,16w+16)
// as 3 A-tiles (r,z,n). After MFMA each thread holds r/z/n gh for its 4 j's and
// its session (col=lane&15) -> elementwise entirely in registers; h kept in
// fp32 regs, mirrored to LDS as swizzled hi/lo bf16 for the next step's B-frag.

// ---------------- bidirectional GRU: 16 sessions/block, grid (63, 2) ----------------
__global__ __launch_bounds__(512) void k_gru_fb(
    const float* __restrict__ Whh_f, const float* __restrict__ Whh_b,
    const float* __restrict__ bhh_f, const float* __restrict__ bhh_b,
    const float* __restrict__ tabf,  const float* __restrict__ tabb,
    const int*   __restrict__ bins,  int Bn,
    float* __restrict__ outf, float* __restrict__ outbrev){
  const int dir = blockIdx.y;
  const int b0  = blockIdx.x * 16;
  const float* Whh = dir ? Whh_b : Whh_f;
  const float* bhh = dir ? bhh_b : bhh_f;
  const float* tab = dir ? tabb  : tabf;
  float* outp = dir ? outbrev : outf;

  __shared__ unsigned short hhi[16*128];   // 4 KB, swizzled [sess][j]
  __shared__ unsigned short hlo[16*128];   // 4 KB
  __shared__ float xts[NBIN*G3];           // 15 KB
  __shared__ int   binr[16][L];

  const int tid = threadIdx.x;
  const int wv = tid>>6, lane = tid&63;
  const int l15 = lane&15, lk = lane>>4;
  const int jb = wv*16;
  const int jq = jb + lk*4;               // first of this thread's 4 j's

  // loop-invariant W fragments: 3 gate-tiles (r,z,n) x 4 K-steps, split hi/lo
  s16x8 whi[3][4], wlo[3][4];
#pragma unroll
  for (int g3i = 0; g3i < 3; ++g3i)
#pragma unroll
    for (int ks = 0; ks < 4; ++ks){
      const f32x4* s = (const f32x4*)&Whh[(size_t)(g3i*D + jb + l15)*D + ks*32 + lk*8];
      split8(s[0], s[1], whi[g3i][ks], wlo[g3i][ks]);
    }
  f32x4 bhv[3];
#pragma unroll
  for (int g3i = 0; g3i < 3; ++g3i) bhv[g3i] = *(const f32x4*)&bhh[g3i*D + jq];

  for (int i = tid; i < NBIN*G3; i += 512) xts[i] = tab[i];
  for (int i = tid; i < 16*L; i += 512){
    int r = i / L, t = i % L;
    binr[r][t] = (b0 + r < Bn) ? bins[(b0+r)*L + (dir ? (L-1-t) : t)] : 0;
  }
  for (int i = tid; i < 16*128; i += 512){ hhi[i] = 0; hlo[i] = 0; }

  const int sess = l15;
  const bool sv = (b0 + sess) < Bn;
  float hreg[4] = {0.f,0.f,0.f,0.f};
  const int wbyte = sess*256 + (((jq>>3) ^ (sess&7))<<4) + ((jq&7)<<1);
  __syncthreads();

  for (int t = 0; t < L; ++t){
    // ---- matmul: gh = Whh_perm @ (h_hi + h_lo)
    f32x4 c0 = {0.f,0.f,0.f,0.f}, c1 = c0, c2 = c0;
#pragma unroll
    for (int ks = 0; ks < 4; ++ks){
      int off = l15*256 + ((((ks<<2)+lk) ^ (l15&7)) << 4);
      s16x8 bh8 = *(const s16x8*)((const char*)hhi + off);
      s16x8 bl8 = *(const s16x8*)((const char*)hlo + off);
      c0 = MFMA_B16(whi[0][ks], bh8, c0); c0 = MFMA_B16(whi[0][ks], bl8, c0); c0 = MFMA_B16(wlo[0][ks], bh8, c0);
      c1 = MFMA_B16(whi[1][ks], bh8, c1); c1 = MFMA_B16(whi[1][ks], bl8, c1); c1 = MFMA_B16(wlo[1][ks], bh8, c1);
      c2 = MFMA_B16(whi[2][ks], bh8, c2); c2 = MFMA_B16(whi[2][ks], bl8, c2); c2 = MFMA_B16(wlo[2][ks], bh8, c2);
    }
    __syncthreads();     // all h reads done before any h writes
    // ---- elementwise, fully in registers
    int bin = binr[sess][t];
    const float* xb = &xts[bin*G3];
    f32x4 xr4 = *(const f32x4*)&xb[jq];
    f32x4 xz4 = *(const f32x4*)&xb[D + jq];
    f32x4 xn4 = *(const f32x4*)&xb[2*D + jq];
    ushort4 hi4, lo4;
    f32x4 hn4;
#pragma unroll
    for (int qq = 0; qq < 4; ++qq){
      float gr = c0[qq] + bhv[0][qq];
      float gz = c1[qq] + bhv[1][qq];
      float gn = c2[qq] + bhv[2][qq];
      float rr = sigm(xr4[qq] + gr);
      float zz = sigm(xz4[qq] + gz);
      float nn = tanh_fast(xn4[qq] + rr*gn);
      float hnew = (1.f-zz)*nn + zz*hreg[qq];
      hreg[qq] = hnew;
      unsigned hu, lu; SPLIT1(hnew, hu, lu)
      ((unsigned short*)&hi4)[qq] = (unsigned short)hu;
      ((unsigned short*)&lo4)[qq] = (unsigned short)lu;
      hn4[qq] = hnew;
    }
    *(ushort4*)((char*)hhi + wbyte) = hi4;
    *(ushort4*)((char*)hlo + wbyte) = lo4;
    if (sv){
      float4 o = make_float4(hn4[0],hn4[1],hn4[2],hn4[3]);
      *(float4*)&outp[((size_t)(b0+sess)*L + (dir ? (L-1-t) : t))*D + jq] = o;
    }
    __syncthreads();
  }
}

// ---------------- e_hat + beta + c (fused, htok gather fused in) ----------------
__global__ __launch_bounds__(256) void k_beta(
    const float* __restrict__ outf, const float* __restrict__ outbrev,
    const float* __restrict__ accA, const int* __restrict__ idxmap,
    const float* __restrict__ w1, const float* __restrict__ w2,
    const float* __restrict__ v3,
    const int* __restrict__ seg, const int* __restrict__ pos, int T,
    float* __restrict__ c_pad, int* __restrict__ tokmap){
  __shared__ float w2s[D*260];        // stride 260: float4-aligned, (j+dd4)%32 banks
  __shared__ float w1s[2*D];
  __shared__ float v3s[D];
  __shared__ float hfs[2][D], ehs[2][D];
  __shared__ float redA[4], redB[4];
  for (int i = threadIdx.x; i < D*2*D; i += 256) w2s[(i/(2*D))*260 + (i%(2*D))] = w2[i];
  for (int i = threadIdx.x; i < 2*D;   i += 256) w1s[i] = w1[i];
  for (int i = threadIdx.x; i < D;     i += 256) v3s[i] = v3[i];
  __syncthreads();
  const int slot = threadIdx.x >> 7;
  const int j    = threadIdx.x & (D-1);
  const int wave = threadIdx.x >> 6;
  const int lane = threadIdx.x & 63;
  for (int t0 = blockIdx.x*2; t0 < T; t0 += gridDim.x*2){
    int t = t0 + slot;
    bool valid = (t < T);
    int sp = 0; float ef = 0.f, eb = 0.f, hfj = 0.f;
    if (valid){
      sp  = seg[t]*L + pos[t];
      ef  = outf[(size_t)sp*D + j];
      eb  = outbrev[(size_t)sp*D + j];
      hfj = 0.25f*accA[(size_t)idxmap[t]*D + j];   // fused hgather, /(LAYER_NUM+1)
    }
    float p = ef*w1s[j] + eb*w1s[D+j];
#pragma unroll
    for (int off = 32; off >= 1; off >>= 1) p += __shfl_down(p, off);
    if (lane == 0) redA[wave] = p;
    __syncthreads();
    float gate = sigm(redA[slot*2] + redA[slot*2+1]);
    float ehj  = gate*ef + (1.f-gate)*eb;
    hfs[slot][j] = hfj;
    ehs[slot][j] = ehj;
    __syncthreads();
    float u = 0.f;
    {
      const f32x4* wr  = (const f32x4*)&w2s[j*260];
      const f32x4* we  = (const f32x4*)&w2s[j*260 + D];
      const f32x4* hf4 = (const f32x4*)hfs[slot];
      const f32x4* eh4 = (const f32x4*)ehs[slot];
#pragma unroll 8
      for (int d4 = 0; d4 < 32; ++d4){
        f32x4 a = wr[d4], b = hf4[d4], c = we[d4], e = eh4[d4];
        u += a[0]*b[0] + a[1]*b[1] + a[2]*b[2] + a[3]*b[3]
           + c[0]*e[0] + c[1]*e[1] + c[2]*e[2] + c[3]*e[3];
      }
    }
    u = tanh_fast(u);
    float pv = u * v3s[j];
#pragma unroll
    for (int off = 32; off >= 1; off >>= 1) pv += __shfl_down(pv, off);
    if (lane == 0) redB[wave] = pv;
    __syncthreads();
    float beta = redB[slot*2] + redB[slot*2+1];
    if (valid){
      c_pad[(size_t)sp*D + j] = beta * hfj;
      if (j == 0) tokmap[sp] = t;
    }
  }
}

// ---------------- z_long ----------------
__global__ void k_zlong(const float* __restrict__ c_pad, float* __restrict__ zl, int Bn){
  int i = blockIdx.x*256 + threadIdx.x;
  if (i >= Bn*D) return;
  int b = i >> 7, j = i & (D-1);
  float s = 0.f;
  for (int l = 0; l < L; ++l) s += c_pad[((size_t)b*L + l)*D + j];
  zl[i] = s;
}

// ---------------- xps[t][g] = dot(c[t], Wih_s[g]) + bih_s[g] ----------------
__global__ __launch_bounds__(G3) void k_xps(
    const float* __restrict__ c_pad, const int* __restrict__ seg,
    const int* __restrict__ pos, const float* __restrict__ Wih,
    const float* __restrict__ bih, int T, float* __restrict__ xps){
  int t0 = blockIdx.x * XT;
  __shared__ float cs[XT][D];
  int nt = min(XT, T - t0);
  for (int i = threadIdx.x; i < XT*D; i += G3){
    int tt = i >> 7, d = i & (D-1);
    float v = 0.f;
    if (tt < nt){
      int t = t0 + tt;
      v = c_pad[(size_t)(seg[t]*L + pos[t])*D + d];
    }
    cs[tt][d] = v;
  }
  __syncthreads();
  int gg = threadIdx.x;
  float acc[XT];
#pragma unroll
  for (int tt = 0; tt < XT; ++tt) acc[tt] = 0.f;
  for (int dc = 0; dc < D; dc += 16){
    float w[16];
#pragma unroll
    for (int k = 0; k < 16; ++k) w[k] = Wih[gg*D + dc + k];
#pragma unroll
    for (int tt = 0; tt < XT; ++tt){
#pragma unroll
      for (int k = 0; k < 16; ++k) acc[tt] += cs[tt][dc+k]*w[k];
    }
  }
  float bi = bih[gg];
  for (int tt = 0; tt < nt; ++tt) xps[(size_t)(t0+tt)*G3 + gg] = acc[tt] + bi;
}

// ---------------- short GRU (fragment-local) + fused final gate ----------------
__global__ __launch_bounds__(512) void k_grus(
    const float* __restrict__ Whh, const float* __restrict__ bhh,
    const float* __restrict__ bih,
    const float* __restrict__ xps, const int* __restrict__ tokmap,
    const float* __restrict__ zl, const float* __restrict__ w3,
    const float* __restrict__ b3, int Bn,
    float* __restrict__ zfin){
  const int b0 = blockIdx.x * 16;

  __shared__ unsigned short hhi[16*128];
  __shared__ unsigned short hlo[16*128];
  __shared__ int   maprow[16][L];
  __shared__ float redg[16];

  const int tid = threadIdx.x;
  const int wv = tid>>6, lane = tid&63;
  const int l15 = lane&15, lk = lane>>4;
  const int jb = wv*16;
  const int jq = jb + lk*4;

  s16x8 whi[3][4], wlo[3][4];
#pragma unroll
  for (int g3i = 0; g3i < 3; ++g3i)
#pragma unroll
    for (int ks = 0; ks < 4; ++ks){
      const f32x4* s = (const f32x4*)&Whh[(size_t)(g3i*D + jb + l15)*D + ks*32 + lk*8];
      split8(s[0], s[1], whi[g3i][ks], wlo[g3i][ks]);
    }
  f32x4 bhv[3], biv[3];
#pragma unroll
  for (int g3i = 0; g3i < 3; ++g3i){
    bhv[g3i] = *(const f32x4*)&bhh[g3i*D + jq];
    biv[g3i] = *(const f32x4*)&bih[g3i*D + jq];
  }
  for (int i = tid; i < 16*L; i += 512){
    int r = i / L, t = i % L;
    maprow[r][t] = (b0 + r < Bn) ? tokmap[(b0+r)*L + t] : -1;
  }
  for (int i = tid; i < 16*128; i += 512){ hhi[i] = 0; hlo[i] = 0; }

  const int sess = l15;
  const bool sv = (b0 + sess) < Bn;
  float hreg[4] = {0.f,0.f,0.f,0.f};
  const int wbyte = sess*256 + (((jq>>3) ^ (sess&7))<<4) + ((jq&7)<<1);
  __syncthreads();

  for (int t = 0; t < L; ++t){
    // prefetch x gates (h-independent -> overlaps MFMA)
    int tok = maprow[sess][t];
    f32x4 xr4, xz4, xn4;
    if (tok >= 0){
      const float* xb = &xps[(size_t)tok*G3];
      xr4 = *(const f32x4*)&xb[jq];
      xz4 = *(const f32x4*)&xb[D + jq];
      xn4 = *(const f32x4*)&xb[2*D + jq];
    } else { xr4 = biv[0]; xz4 = biv[1]; xn4 = biv[2]; }
    // ---- matmul
    f32x4 c0 = {0.f,0.f,0.f,0.f}, c1 = c0, c2 = c0;
#pragma unroll
    for (int ks = 0; ks < 4; ++ks){
      int off = l15*256 + ((((ks<<2)+lk) ^ (l15&7)) << 4);
      s16x8 bh8 = *(const s16x8*)((const char*)hhi + off);
      s16x8 bl8 = *(const s16x8*)((const char*)hlo + off);
      c0 = MFMA_B16(whi[0][ks], bh8, c0); c0 = MFMA_B16(whi[0][ks], bl8, c0); c0 = MFMA_B16(wlo[0][ks], bh8, c0);
      c1 = MFMA_B16(whi[1][ks], bh8, c1); c1 = MFMA_B16(whi[1][ks], bl8, c1); c1 = MFMA_B16(wlo[1][ks], bh8, c1);
      c2 = MFMA_B16(whi[2][ks], bh8, c2); c2 = MFMA_B16(whi[2][ks], bl8, c2); c2 = MFMA_B16(wlo[2][ks], bh8, c2);
    }
    __syncthreads();
    ushort4 hi4, lo4;
#pragma unroll
    for (int qq = 0; qq < 4; ++qq){
      float gr = c0[qq] + bhv[0][qq];
      float gz = c1[qq] + bhv[1][qq];
      float gn = c2[qq] + bhv[2][qq];
      float rr = sigm(xr4[qq] + gr);
      float zz = sigm(xz4[qq] + gz);
      float nn = tanh_fast(xn4[qq] + rr*gn);
      float hnew = (1.f-zz)*nn + zz*hreg[qq];
      hreg[qq] = hnew;
      unsigned hu, lu; SPLIT1(hnew, hu, lu)
      ((unsigned short*)&hi4)[qq] = (unsigned short)hu;
      ((unsigned short*)&lo4)[qq] = (unsigned short)lu;
    }
    *(ushort4*)((char*)hhi + wbyte) = hi4;
    *(ushort4*)((char*)hlo + wbyte) = lo4;
    __syncthreads();
  }

  // ---- fused final gate: zfin = f*zl + (1-f)*h_final
  if (tid < 16) redg[tid] = 0.f;
  __syncthreads();
  f32x4 zl4 = {0.f,0.f,0.f,0.f};
  if (sv) zl4 = *(const f32x4*)&zl[(size_t)(b0+sess)*D + jq];
  f32x4 w34 = *(const f32x4*)&w3[jq];
  float part = 0.f;
#pragma unroll
  for (int qq = 0; qq < 4; ++qq) part += (zl4[qq] + hreg[qq]) * w34[qq];
  if (sv) atomicAdd(&redg[sess], part);
  __syncthreads();
  if (sv){
    float f = sigm(redg[sess] + b3[0]);
    f32x4 zf4;
#pragma unroll
    for (int qq = 0; qq < 4; ++qq) zf4[qq] = f*zl4[qq] + (1.f-f)*hreg[qq];
    *(f32x4*)&zfin[(size_t)(b0+sess)*D + jq] = zf4;
  }
}

// ---------------- out = z_final @ item_emb.T  (split-bf16 MFMA, A in regs) ----------------
__global__ __launch_bounds__(256,2) void k_fmm(
    const float* __restrict__ zfin, const float* __restrict__ emb,
    float* __restrict__ out, int NI, int Bsz){
  __shared__ unsigned short Bh[FBN*64], Bl[FBN*64];   // 32 KB

  int nwg = gridDim.x;
  int hw  = blockIdx.x;
  int q8 = nwg >> 3, r8 = nwg & 7;
  int xcd = hw & 7, idx = hw >> 3;
  int logical = (xcd < r8 ? xcd*(q8+1) : r8*(q8+1) + (xcd-r8)*q8) + idx;
  int ntile = logical >> 3;       // 8 consecutive logicals share an emb tile
  int mtile = logical & 7;
  int m0 = mtile*FBM;
  int n0 = ntile*FBN;

  const int t    = threadIdx.x;
  const int lane = t & 63;
  const int wid  = t >> 6;
  const int wm   = wid >> 1, wn = wid & 1;   // 2x2 wave grid, 64x64 each
  const int l15  = lane & 15, lk = lane >> 4;

  f32x4 acc[4][4];
#pragma unroll
  for (int i = 0; i < 4; ++i)
#pragma unroll
    for (int jj = 0; jj < 4; ++jj){ f32x4 z4 = {0.f,0.f,0.f,0.f}; acc[i][jj] = z4; }

  for (int kc = 0; kc < 2; ++kc){
    // ---- A (z rows): global -> regs -> split (z is 512KB, L2/L3-hot)
    s16x8 ahi[4][2], alo[4][2];
#pragma unroll
    for (int mf = 0; mf < 4; ++mf)
#pragma unroll
      for (int ks = 0; ks < 2; ++ks){
        int m = m0 + wm*64 + mf*16 + l15;
        f32x4 x0 = {0.f,0.f,0.f,0.f}, x1 = x0;
        if (m < Bsz){
          const f32x4* src = (const f32x4*)&zfin[(size_t)m*D + kc*64 + ks*32 + lk*8];
          x0 = src[0]; x1 = src[1];
        }
        split8(x0, x1, ahi[mf][ks], alo[mf][ks]);
      }
    // ---- B (emb rows): stage to swizzled LDS
#pragma unroll
    for (int p = 0; p < 4; ++p){
      int row  = p*32 + (t>>3);
      int slot = t & 7;
      int item = n0 + row;
      f32x4 x0 = {0.f,0.f,0.f,0.f}, x1 = x0;
      if (item < NI){
        const f32x4* src = (const f32x4*)&emb[(size_t)item*D + kc*64 + slot*8];
        x0 = src[0]; x1 = src[1];
      }
      s16x8 hv, lv;
      split8(x0, x1, hv, lv);
      int byte = row*128 + ((slot ^ (row&7))<<4);
      *(s16x8*)((char*)Bh + byte) = hv;
      *(s16x8*)((char*)Bl + byte) = lv;
    }
    __syncthreads();
    // ---- compute
#pragma unroll
    for (int ks = 0; ks < 2; ++ks){
      s16x8 bh8[4], bl8[4];
#pragma unroll
      for (int nf = 0; nf < 4; ++nf){
        int row = wn*64 + nf*16 + l15;
        int byte = row*128 + ((((ks<<2)+lk) ^ (row&7))<<4);
        bh8[nf] = *(const s16x8*)((const char*)Bh + byte);
        bl8[nf] = *(const s16x8*)((const char*)Bl + byte);
      }
#pragma unroll
      for (int mf = 0; mf < 4; ++mf)
#pragma unroll
        for (int nf = 0; nf < 4; ++nf){
          acc[mf][nf] = MFMA_B16(ahi[mf][ks], bh8[nf], acc[mf][nf]);
          acc[mf][nf] = MFMA_B16(ahi[mf][ks], bl8[nf], acc[mf][nf]);
          acc[mf][nf] = MFMA_B16(alo[mf][ks], bh8[nf], acc[mf][nf]);
        }
    }
    __syncthreads();
  }

#pragma unroll
  for (int mf = 0; mf < 4; ++mf){
    int rowb = m0 + wm*64 + mf*16 + lk*4;
#pragma unroll
    for (int nf = 0; nf < 4; ++nf){
      int col = n0 + wn*64 + nf*16 + l15;
      if (col < NI){
#pragma unroll
        for (int qq = 0; qq < 4; ++qq){
          int rr = rowb + qq;
          if (rr < Bsz) out[(size_t)rr*NI + col] = acc[mf][nf][qq];
        }
      }
    }
  }
}

extern "C" void kernel_launch(void* const* d_in, const int* in_sizes, int n_in,
                              void* d_out, int out_size, void* d_ws, size_t ws_size,
                              hipStream_t stream){
  const int*   items    = (const int*)d_in[0];
  const int*   edge     = (const int*)d_in[1];
  const float* ew       = (const float*)d_in[2];
  const int*   item2idx = (const int*)d_in[3];
  const int*   bins     = (const int*)d_in[4];
  const int*   seg      = (const int*)d_in[5];
  const int*   pos      = (const int*)d_in[6];
  const float* item_emb = (const float*)d_in[8];
  const float* bin_emb  = (const float*)d_in[9];
  const float* Wih_f = (const float*)d_in[10];
  const float* Whh_f = (const float*)d_in[11];
  const float* bih_f = (const float*)d_in[12];
  const float* bhh_f = (const float*)d_in[13];
  const float* Wih_b = (const float*)d_in[14];
  const float* Whh_b = (const float*)d_in[15];
  const float* bih_b = (const float*)d_in[16];
  const float* bhh_b = (const float*)d_in[17];
  const float* w1    = (const float*)d_in[18];
  const float* w2    = (const float*)d_in[19];
  const float* v3    = (const float*)d_in[20];
  const float* Wih_s = (const float*)d_in[21];
  const float* Whh_s = (const float*)d_in[22];
  const float* bih_s = (const float*)d_in[23];
  const float* bhh_s = (const float*)d_in[24];
  const float* w3    = (const float*)d_in[25];
  const float* b3    = (const float*)d_in[26];
  float* out = (float*)d_out;

  const int NN = in_sizes[0];          // 25500 graph nodes
  const int NE = in_sizes[2];          // 51000 edges
  const int T  = in_sizes[3];          // 25500 tokens
  const int B  = in_sizes[7];          // 1000 sessions
  const int NI = in_sizes[8] / D;      // 100000 items

  const size_t NG  = (size_t)NN * D;   // 3,264,000
  const size_t BLD = (size_t)B * L * D;

  float* ws   = (float*)d_ws;
  float* accA = ws;
  float* xB   = ws + NG;
  float* xC   = ws + 2*NG;
  float* xps  = ws;                    // reuse accA..xC after k_beta (3NG == T*G3)
  float* outf = ws + 3*NG;
  float* outb = outf + BLD;
  float* cpad = outb + BLD;
  int*   tokmap = (int*)(cpad + BLD);
  float* tabf = (float*)(tokmap + (size_t)B*L);
  float* tabb = tabf + NBIN*G3;
  float* zl   = tabb + NBIN*G3;
  float* zfin = zl + (size_t)B*D;

  const int sgrid = (int)((NG + 255)/256);

  // 1) prep: tables + h0 init (accA,xB) + zero xC/cpad + tokmap=-1
  hipLaunchKernelGGL(k_prep, dim3(2048), dim3(256), 0, stream,
                     bin_emb, Wih_f, bih_f, Wih_b, bih_b, item_emb, items,
                     tabf, tabb, accA, xB, xC, cpad, tokmap,
                     (long long)NG, (long long)BLD, B*L);
  // 2) GCN: 3 x {scatter, accum(+zero next)}
  hipLaunchKernelGGL(k_scatter, dim3((unsigned)(((size_t)NE*D+255)/256)), dim3(256), 0, stream,
                     xB, xC, edge, edge+NE, ew, NE);
  hipLaunchKernelGGL(k_accum_zero, dim3(sgrid), dim3(256), 0, stream, accA, xC, xB, (int)NG, 1);
  hipLaunchKernelGGL(k_scatter, dim3((unsigned)(((size_t)NE*D+255)/256)), dim3(256), 0, stream,
                     xC, xB, edge, edge+NE, ew, NE);
  hipLaunchKernelGGL(k_accum_zero, dim3(sgrid), dim3(256), 0, stream, accA, xB, xC, (int)NG, 1);
  hipLaunchKernelGGL(k_scatter, dim3((unsigned)(((size_t)NE*D+255)/256)), dim3(256), 0, stream,
                     xB, xC, edge, edge+NE, ew, NE);
  hipLaunchKernelGGL(k_accum_zero, dim3(sgrid), dim3(256), 0, stream, accA, xC, (float*)0, (int)NG, 0);
  // 3) bidirectional GRU (fragment-local MFMA)
  hipLaunchKernelGGL(k_gru_fb, dim3((B+15)/16, 2), dim3(512), 0, stream,
                     Whh_f, Whh_b, bhh_f, bhh_b, tabf, tabb, bins, B, outf, outb);
  // 4) fused e_hat/beta/c (htok gathered from accA inside)
  hipLaunchKernelGGL(k_beta, dim3(256), dim3(256), 0, stream,
                     outf, outb, accA, item2idx, w1, w2, v3, seg, pos, T, cpad, tokmap);
  // 5) z_long
  hipLaunchKernelGGL(k_zlong, dim3((B*D+255)/256), dim3(256), 0, stream, cpad, zl, B);
  // 6) xps for short GRU (reuses accA..xC region)
  hipLaunchKernelGGL(k_xps, dim3((T+XT-1)/XT), dim3(G3), 0, stream,
                     cpad, seg, pos, Wih_s, bih_s, T, xps);
  // 7) short GRU + fused final gate -> zfin
  hipLaunchKernelGGL(k_grus, dim3((B+15)/16), dim3(512), 0, stream,
                     Whh_s, bhh_s, bih_s, xps, tokmap, zl, w3, b3, B, zfin);
  // 8) out = z_final @ item_emb.T
  {
    int mtiles = (B + FBM - 1)/FBM;        // 8
    int ntiles = (NI + FBN - 1)/FBN;       // 782
    hipLaunchKernelGGL(k_fmm, dim3(mtiles*ntiles), dim3(256), 0, stream,
                       zfin, item_emb, out, NI, B);
  }
}